// Round 10
// baseline (93.864 us; speedup 1.0000x reference)
//
#include <hip/hip_runtime.h>
#include <hip/hip_bf16.h>

typedef short bf16x8 __attribute__((ext_vector_type(8)));
typedef float f32x4  __attribute__((ext_vector_type(4)));

#define T_AUDIO 262144
#define PADL 384
#define CUTOFF 513
#define CPAD 576       // padded mel K (513 -> 576)
#define NMELS 80
#define SEGLEN 33536   // 127*256 + 1024 samples per 128-frame tile
#define EBYTES 33536   // SEGLEN/2 bf16 = bytes per parity plane in LDS

__device__ __forceinline__ unsigned short f2bf(float f){
  union { float f; unsigned u; } v; v.f = f;
  return (unsigned short)((v.u + 0x7FFFu + ((v.u >> 16) & 1u)) >> 16);
}

__device__ __forceinline__ void gload_lds16(const void* g, void* l){
  __builtin_amdgcn_global_load_lds(
      (const __attribute__((address_space(1))) unsigned int*)g,
      (__attribute__((address_space(3))) unsigned int*)l, 16, 0, 0);
}

// ---------- k_basis4: frag-major A  bi2f[(((g*2+p)*16+s)*8+f)*64+l] 16B chunks ----------
__global__ void k_basis4(const float* __restrict__ basis, unsigned short* __restrict__ bi2f){
  int CI = blockIdx.x * 256 + threadIdx.x;     // 65536 chunks
  int l  = CI & 63;
  int f  = (CI >> 6) & 7;
  int s  = (CI >> 9) & 15;
  int p  = (CI >> 13) & 1;
  int g  = CI >> 14;
  int R  = g * 128 + (f >> 2) * 64 + (f & 3) * 16 + (l & 15);
  int srcr = (R >> 1) + 513 * (R & 1);
  const float* sp = basis + srcr * 1024 + 2 * (s * 32 + (l >> 4) * 8) + p;
  bf16x8 o;
  #pragma unroll
  for (int e = 0; e < 8; ++e) o[e] = (short)f2bf(sp[2*e]);
  *(bf16x8*)(bi2f + (long)CI * 8) = o;
}

// ---------- k_w: mel weights [80][576] bf16, zero-padded ----------
__global__ void k_w(const float* __restrict__ w, unsigned short* __restrict__ wb){
  int gid = blockIdx.x * 256 + threadIdx.x;
  if (gid >= NMELS * CPAD) return;
  int m = gid / CPAD, c = gid % CPAD;
  float v = (c < CUTOFF) ? w[m * CUTOFF + c] : 0.f;
  wb[gid] = f2bf(v);
}

// ---------- k_stft: barrier-free E/O GEMM + transpose epilogue + fused bin-256 ----------
__launch_bounds__(256, 2)
__global__ void k_stft(const unsigned short* __restrict__ bi2f,
                       const float* __restrict__ audio,
                       const float* __restrict__ basis,
                       unsigned short* __restrict__ magT){
  __shared__ __align__(16) char LDS[2 * EBYTES];   // evens | odds ; reused for transpose
  const int tid = threadIdx.x;
  const int l   = tid & 63, w = tid >> 6;
  const int wm  = w >> 1, wn = w & 1;
  const int x   = l & 15, h = l >> 4;

  int bx = blockIdx.x;
  int sw = ((bx & 7) << 7) | (bx >> 3);   // XCD swizzle (1024 % 8 == 0, bijective)
  const int g  = sw & 3;
  const int nt = sw >> 2;                 // frames [nt*128, +128)

  // ---- stage audio segment once: evens/odds bf16, chunk XOR swizzle ----
  {
    const long segbase = (long)(nt >> 3) * T_AUDIO;
    const int  f0 = (nt & 7) << 7;
    const int  sstart = f0 * 256 - PADL;
    const float* ap = audio + segbase;
    #pragma unroll
    for (int it = 0; it < 17; ++it){
      int p0 = (it * 256 + tid) * 8;
      if (p0 < SEGLEN){
        int sg = sstart + p0;
        float v[8];
        if (sg >= 0 && sg + 7 < T_AUDIO){
          f32x4 a0 = *(const f32x4*)(ap + sg);
          f32x4 a1 = *(const f32x4*)(ap + sg + 4);
          v[0]=a0[0]; v[1]=a0[1]; v[2]=a0[2]; v[3]=a0[3];
          v[4]=a1[0]; v[5]=a1[1]; v[6]=a1[2]; v[7]=a1[3];
        } else {
          #pragma unroll
          for (int e = 0; e < 8; ++e){
            int ss = sg + e;
            if (ss < 0) ss = -ss;
            if (ss >= T_AUDIO) ss = 2*(T_AUDIO-1) - ss;
            v[e] = ap[ss];
          }
        }
        unsigned long long pe = (unsigned long long)f2bf(v[0])
                              | ((unsigned long long)f2bf(v[2]) << 16)
                              | ((unsigned long long)f2bf(v[4]) << 32)
                              | ((unsigned long long)f2bf(v[6]) << 48);
        unsigned long long po = (unsigned long long)f2bf(v[1])
                              | ((unsigned long long)f2bf(v[3]) << 16)
                              | ((unsigned long long)f2bf(v[5]) << 32)
                              | ((unsigned long long)f2bf(v[7]) << 48);
        int ep = p0 >> 1;
        int C  = ep >> 3;
        int ad = ((C ^ ((C >> 4) & 15)) << 4) + ((ep & 4) << 1);
        *(unsigned long long*)(LDS + ad)          = pe;
        *(unsigned long long*)(LDS + EBYTES + ad) = po;
      }
    }
  }
  __syncthreads();

  // ---- A frag-major bases (L2-resident) ----
  const char* AgE = (const char*)bi2f + (long)(g * 256 + wm * 4) * 1024 + l * 16;
  const char* AgO = AgE + 131072;

  int C0[4];
  #pragma unroll
  for (int j = 0; j < 4; ++j) C0[j] = (wn * 64 + j * 16 + x) * 16 + h;

  f32x4 accE[4][4] = {}, accO[4][4] = {};
  bf16x8 aE[2][4], aO[2][4];
  #pragma unroll
  for (int i = 0; i < 4; ++i){
    aE[0][i] = *(const bf16x8*)(AgE + i * 1024);
    aO[0][i] = *(const bf16x8*)(AgO + i * 1024);
  }

  #pragma unroll
  for (int s = 0; s < 16; ++s){
    const int cur = s & 1, nxt = cur ^ 1;
    if (s < 15){
      #pragma unroll
      for (int i = 0; i < 4; ++i){
        aE[nxt][i] = *(const bf16x8*)(AgE + (s + 1) * 8192 + i * 1024);
        aO[nxt][i] = *(const bf16x8*)(AgO + (s + 1) * 8192 + i * 1024);
      }
    }
    bf16x8 bqE[4], bqO[4];
    #pragma unroll
    for (int j = 0; j < 4; ++j){
      int C  = C0[j] + s * 4;
      int ad = (C ^ ((C >> 4) & 15)) << 4;
      bqE[j] = *(const bf16x8*)(LDS + ad);
      bqO[j] = *(const bf16x8*)(LDS + EBYTES + ad);
    }
    __builtin_amdgcn_s_setprio(1);
    #pragma unroll
    for (int i = 0; i < 4; ++i)
      #pragma unroll
      for (int j = 0; j < 4; ++j)
        accE[i][j] = __builtin_amdgcn_mfma_f32_16x16x32_bf16(aE[cur][i], bqE[j], accE[i][j], 0, 0, 0);
    #pragma unroll
    for (int i = 0; i < 4; ++i)
      #pragma unroll
      for (int j = 0; j < 4; ++j)
        accO[i][j] = __builtin_amdgcn_mfma_f32_16x16x32_bf16(aO[cur][i], bqO[j], accO[i][j], 0, 0, 0);
    __builtin_amdgcn_s_setprio(0);
  }

  // ---- fused bin-256 for frames [g*32, g*32+32): re over E-plane, im over O-plane ----
  const long rowbase = (long)(nt * 128) * CPAD;
  {
    int fl   = tid >> 3;                 // 0..31
    int p    = (tid >> 2) & 1;           // 0=re(E), 1=im(O)
    int sub  = tid & 3;
    int frame = g * 32 + fl;
    const char* plane = LDS + p * EBYTES;
    const float* brow = basis + (p ? (769 * 1024 + 1) : (256 * 1024));
    float ssum = 0.f;
    #pragma unroll 4
    for (int m = sub * 128; m < sub * 128 + 128; ++m){
      int e = frame * 128 + m;
      int C = e >> 3;
      int ad = ((C ^ ((C >> 4) & 15)) << 4) + (e & 7) * 2;
      unsigned u = *(const unsigned short*)(plane + ad);
      union { unsigned u; float f; } cv; cv.u = u << 16;
      ssum += cv.f * brow[2 * m];
    }
    ssum += __shfl_xor(ssum, 1, 64);
    ssum += __shfl_xor(ssum, 2, 64);
    float other = __shfl_down(ssum, 4, 64);
    if ((tid & 7) == 0)
      magT[rowbase + (long)frame * CPAD + 256] = f2bf(sqrtf(ssum*ssum + other*other));
  }
  __syncthreads();   // all LDS audio reads done; safe to overwrite

  // ---- transpose tile fill: u16 [128 t][128 slots], cpair swizzled by t ----
  #pragma unroll
  for (int i = 0; i < 4; ++i){
    int c0l = wm * 32 + i * 8 + (h << 1);    // local c 0..63 (even)
    int cp1 = c0l >> 1;
    int cp2 = 63 - cp1;
    #pragma unroll
    for (int j = 0; j < 4; ++j){
      int tl = wn * 64 + j * 16 + x;
      f32x4 E = accE[i][j], O = accO[i][j];
      float m1 = sqrtf((E[0]+O[0])*(E[0]+O[0]) + (E[1]+O[1])*(E[1]+O[1]));  // c0
      float m2 = sqrtf((E[2]+O[2])*(E[2]+O[2]) + (E[3]+O[3])*(E[3]+O[3]));  // c0+1
      float m3 = sqrtf((E[0]-O[0])*(E[0]-O[0]) + (E[1]-O[1])*(E[1]-O[1]));  // 512-c0
      float m4 = sqrtf((E[2]-O[2])*(E[2]-O[2]) + (E[3]-O[3])*(E[3]-O[3]));  // 511-c0
      unsigned p1 = (unsigned)f2bf(m1) | ((unsigned)f2bf(m2) << 16);
      unsigned p2 = (unsigned)f2bf(m4) | ((unsigned)f2bf(m3) << 16);
      *(unsigned*)(LDS + tl * 256 + ((cp1 ^ (tl & 31)) << 2)) = p1;
      *(unsigned*)(LDS + tl * 256 + ((cp2 ^ (tl & 31)) << 2)) = p2;
    }
  }
  __syncthreads();

  // ---- coalesced readout: one wave stores one (t,half) 64x u16 = 128 B per iter ----
  const int cdir = 64 * g, cmir = 449 - 64 * g;
  for (int it2 = 0; it2 < 64; ++it2){
    int pair = it2 * 4 + w;                  // 0..255
    int tl = pair >> 1, half = pair & 1;
    int slot = half * 64 + l;
    int cp = slot >> 1;
    unsigned short v = *(const unsigned short*)(LDS + tl * 256 + ((cp ^ (tl & 31)) << 2) + (slot & 1) * 2);
    int c = half ? (cmir + l) : (cdir + l);
    magT[rowbase + (long)tl * CPAD + c] = v;
  }
  // ---- zero cols 513..575 for this block's 32 t's (guards first-call NaN garbage) ----
  for (int it3 = 0; it3 < 8; ++it3){
    int tl = g * 32 + it3 * 4 + w;
    if (l < 63) magT[rowbase + (long)tl * CPAD + 513 + l] = 0;
  }
}

// ---------- k_mel: [80][576] x [576][t] + log(clip) -> out [32][80][1024] f32 ----------
__launch_bounds__(256)
__global__ void k_mel(const unsigned short* __restrict__ wb,
                      const unsigned short* __restrict__ magT,
                      float* __restrict__ out){
  __shared__ unsigned short Ws[80 * 32];
  __shared__ unsigned short Ms[128 * 32];
  int tid  = threadIdx.x, lane = tid & 63, wid = tid >> 6;
  int bx   = blockIdx.x;
  int bt   = bx & 7, b = bx >> 3;
  int t0   = bt * 128;
  f32x4 acc[5][2] = {};
  const char* Mb = (const char*)(magT + ((long)b * 1024 + t0) * CPAD);
  const char* Wb = (const char*)wb;

  for (int kt = 0; kt < 18; ++kt){
    int k0b = kt * 64;
    {
      int o = tid * 16;
      gload_lds16(Wb + (o >> 6) * 1152 + k0b + (o & 63), (char*)Ws + wid * 1024);
      if (wid == 0){
        int o2 = 4096 + lane * 16;
        gload_lds16(Wb + (o2 >> 6) * 1152 + k0b + (o2 & 63), (char*)Ws + 4096);
      }
    }
    #pragma unroll
    for (int q = 0; q < 2; ++q){
      int o = (q * 256 + tid) * 16;
      gload_lds16(Mb + (long)(o >> 6) * 1152 + k0b + (o & 63), (char*)Ms + q * 4096 + wid * 1024);
    }
    __syncthreads();
    bf16x8 af[5], bfr[2];
    int kb = (lane >> 4) << 4;
    #pragma unroll
    for (int i = 0; i < 5; ++i)
      af[i] = *(const bf16x8*)((const char*)Ws + (i*16 + (lane & 15)) * 64 + kb);
    #pragma unroll
    for (int j = 0; j < 2; ++j)
      bfr[j] = *(const bf16x8*)((const char*)Ms + (wid*32 + j*16 + (lane & 15)) * 64 + kb);
    #pragma unroll
    for (int i = 0; i < 5; ++i)
      #pragma unroll
      for (int j = 0; j < 2; ++j)
        acc[i][j] = __builtin_amdgcn_mfma_f32_16x16x32_bf16(af[i], bfr[j], acc[i][j], 0, 0, 0);
    __syncthreads();
  }
  #pragma unroll
  for (int i = 0; i < 5; ++i)
    #pragma unroll
    for (int j = 0; j < 2; ++j){
      int m = i*16 + ((lane >> 4) << 2);
      int t = t0 + wid*32 + j*16 + (lane & 15);
      #pragma unroll
      for (int r = 0; r < 4; ++r){
        float v = acc[i][j][r];
        out[((long)b * NMELS + (m + r)) * 1024 + t] = logf(fmaxf(v, 1e-5f));
      }
    }
}

__global__ void k_sentinel(float* out, int n){
  int i = blockIdx.x * 256 + threadIdx.x;
  if (i < n) out[i] = 12345.0f;
}

extern "C" void kernel_launch(void* const* d_in, const int* in_sizes, int n_in,
                              void* d_out, int out_size, void* d_ws, size_t ws_size,
                              hipStream_t stream){
  const float* audio = (const float*)d_in[0];
  const float* basis = (const float*)d_in[1];
  const float* melw  = (const float*)d_in[2];
  float* out = (float*)d_out;

  size_t off_bi  = 0;                                            // bi2f: 1 MB
  size_t off_wb  = (size_t)1024 * 1024;
  size_t off_mag = off_wb + (size_t)NMELS * CPAD * 2;
  size_t total   = off_mag + (size_t)32 * 1024 * CPAD * 2;       // ~38.9 MB

  if (ws_size < total){
    k_sentinel<<<(out_size + 255) / 256, 256, 0, stream>>>(out, out_size);
    return;
  }
  char* ws = (char*)d_ws;
  unsigned short* bi2f = (unsigned short*)(ws + off_bi);
  unsigned short* wb   = (unsigned short*)(ws + off_wb);
  unsigned short* magT = (unsigned short*)(ws + off_mag);

  k_basis4<<<  256, 256, 0, stream>>>(basis, bi2f);
  k_w     <<<  180, 256, 0, stream>>>(melw, wb);
  k_stft  <<< 1024, 256, 0, stream>>>(bi2f, audio, basis, magT);
  k_mel   <<<  256, 256, 0, stream>>>(wb, magT, out);
}

// Round 11
// 81.132 us; speedup vs baseline: 1.1569x; 1.1569x over previous
//
#include <hip/hip_runtime.h>
#include <hip/hip_bf16.h>

typedef short bf16x8 __attribute__((ext_vector_type(8)));
typedef float f32x4  __attribute__((ext_vector_type(4)));
typedef int   i32x4  __attribute__((ext_vector_type(4)));

#define T_AUDIO 262144
#define PADL 384
#define CUTOFF 513
#define CPAD 576       // padded mel K; layout: p=c for c<=256, hole 257..263, p=c+7 for c>=257, tail 520..575 zero
#define NMELS 80
#define SEGLEN 33536   // 127*256 + 1024 samples per 128-frame tile
#define EBYTES 33536   // SEGLEN/2 bf16 = bytes per parity plane in LDS

__device__ __forceinline__ unsigned short f2bf(float f){
  union { float f; unsigned u; } v; v.f = f;
  return (unsigned short)((v.u + 0x7FFFu + ((v.u >> 16) & 1u)) >> 16);
}

__device__ __forceinline__ void gload_lds16(const void* g, void* l){
  __builtin_amdgcn_global_load_lds(
      (const __attribute__((address_space(1))) unsigned int*)g,
      (__attribute__((address_space(3))) unsigned int*)l, 16, 0, 0);
}

// ---------- k_extra: bin-256 column (f32 dot) + zero pad cols (hole 257..263, tail 520..575) ----------
__global__ void k_extra(const float* __restrict__ audio,
                        const float* __restrict__ basis,
                        unsigned short* __restrict__ magT){
  __shared__ float swr[4], swi[4];
  int tid = threadIdx.x;
  int gid = blockIdx.x * 256 + tid;
  int b   = gid >> 17;
  int rem = gid & 131071;
  int t   = rem >> 7;
  int k0  = (rem & 127) << 3;
  int s0  = t * 256 + k0 - PADL;
  const float* ap = audio + (long)b * T_AUDIO;
  float v[8];
  if (s0 >= 0 && s0 + 7 < T_AUDIO){
    f32x4 a0 = *(const f32x4*)(ap + s0);
    f32x4 a1 = *(const f32x4*)(ap + s0 + 4);
    v[0]=a0[0]; v[1]=a0[1]; v[2]=a0[2]; v[3]=a0[3];
    v[4]=a1[0]; v[5]=a1[1]; v[6]=a1[2]; v[7]=a1[3];
  } else {
    #pragma unroll
    for (int e = 0; e < 8; ++e){
      int s = s0 + e;
      if (s < 0) s = -s;
      if (s >= T_AUDIO) s = 2*(T_AUDIO-1) - s;
      v[e] = ap[s];
    }
  }
  const float* r256 = basis + 256 * 1024 + k0;
  const float* i256 = basis + 769 * 1024 + k0;
  float dr = 0.f, di = 0.f;
  #pragma unroll
  for (int e = 0; e < 8; ++e){ dr += v[e]*r256[e]; di += v[e]*i256[e]; }
  #pragma unroll
  for (int off = 32; off; off >>= 1){
    dr += __shfl_down(dr, off, 64);
    di += __shfl_down(di, off, 64);
  }
  int lane = tid & 63, wid = tid >> 6;
  if (lane == 0){ swr[wid] = dr; swi[wid] = di; }
  __syncthreads();
  long tg = (long)b * 1024 + t;
  if (tid == 0 || tid == 128){
    float R = (tid == 0) ? (swr[0] + swr[1]) : (swr[2] + swr[3]);
    float I = (tid == 0) ? (swi[0] + swi[1]) : (swi[2] + swi[3]);
    magT[tg * CPAD + 256] = f2bf(sqrtf(R*R + I*I));
  }
  int c = tid & 127;
  if (c < 63){
    int p = (c < 7) ? (257 + c) : (513 + c);   // 257..263 and 520..575
    magT[tg * CPAD + p] = 0;
  }
}

// ---------- k_basis4: frag-major A  bi2f[(((g*2+p)*16+s)*8+f)*64+l] 16B chunks ----------
__global__ void k_basis4(const float* __restrict__ basis, unsigned short* __restrict__ bi2f){
  int CI = blockIdx.x * 256 + threadIdx.x;     // 65536 chunks
  int l  = CI & 63;
  int f  = (CI >> 6) & 7;
  int s  = (CI >> 9) & 15;
  int p  = (CI >> 13) & 1;
  int g  = CI >> 14;
  int R  = g * 128 + (f >> 2) * 64 + (f & 3) * 16 + (l & 15);
  int srcr = (R >> 1) + 513 * (R & 1);
  const float* sp = basis + srcr * 1024 + 2 * (s * 32 + (l >> 4) * 8) + p;
  bf16x8 o;
  #pragma unroll
  for (int e = 0; e < 8; ++e) o[e] = (short)f2bf(sp[2*e]);
  *(bf16x8*)(bi2f + (long)CI * 8) = o;
}

// ---------- k_w: mel weights [80][576] bf16, mirror-shifted (+7) layout ----------
__global__ void k_w(const float* __restrict__ w, unsigned short* __restrict__ wb){
  int gid = blockIdx.x * 256 + threadIdx.x;
  if (gid >= NMELS * CPAD) return;
  int m = gid / CPAD, p = gid % CPAD;
  float v = 0.f;
  if (p <= 256) v = w[m * CUTOFF + p];
  else if (p >= 264 && p <= 519) v = w[m * CUTOFF + (p - 7)];
  wb[gid] = f2bf(v);
}

// ---------- k_stft: barrier-free E/O GEMM + aligned transpose epilogue ----------
__launch_bounds__(256, 2)
__global__ void k_stft(const unsigned short* __restrict__ bi2f,
                       const float* __restrict__ audio,
                       unsigned short* __restrict__ magT){
  __shared__ __align__(16) char LDS[2 * EBYTES];   // evens | odds ; reused for transpose
  const int tid = threadIdx.x;
  const int l   = tid & 63, w = tid >> 6;
  const int wm  = w >> 1, wn = w & 1;
  const int x   = l & 15, h = l >> 4;

  int bx = blockIdx.x;
  int sw = ((bx & 7) << 7) | (bx >> 3);   // XCD swizzle (1024 % 8 == 0, bijective)
  const int g  = sw & 3;
  const int nt = sw >> 2;                 // frames [nt*128, +128)

  // ---- stage audio segment once: evens/odds bf16, chunk XOR swizzle ----
  {
    const long segbase = (long)(nt >> 3) * T_AUDIO;
    const int  f0 = (nt & 7) << 7;
    const int  sstart = f0 * 256 - PADL;
    const float* ap = audio + segbase;
    #pragma unroll
    for (int it = 0; it < 17; ++it){
      int p0 = (it * 256 + tid) * 8;
      if (p0 < SEGLEN){
        int sg = sstart + p0;
        float v[8];
        if (sg >= 0 && sg + 7 < T_AUDIO){
          f32x4 a0 = *(const f32x4*)(ap + sg);
          f32x4 a1 = *(const f32x4*)(ap + sg + 4);
          v[0]=a0[0]; v[1]=a0[1]; v[2]=a0[2]; v[3]=a0[3];
          v[4]=a1[0]; v[5]=a1[1]; v[6]=a1[2]; v[7]=a1[3];
        } else {
          #pragma unroll
          for (int e = 0; e < 8; ++e){
            int ss = sg + e;
            if (ss < 0) ss = -ss;
            if (ss >= T_AUDIO) ss = 2*(T_AUDIO-1) - ss;
            v[e] = ap[ss];
          }
        }
        unsigned long long pe = (unsigned long long)f2bf(v[0])
                              | ((unsigned long long)f2bf(v[2]) << 16)
                              | ((unsigned long long)f2bf(v[4]) << 32)
                              | ((unsigned long long)f2bf(v[6]) << 48);
        unsigned long long po = (unsigned long long)f2bf(v[1])
                              | ((unsigned long long)f2bf(v[3]) << 16)
                              | ((unsigned long long)f2bf(v[5]) << 32)
                              | ((unsigned long long)f2bf(v[7]) << 48);
        int ep = p0 >> 1;
        int C  = ep >> 3;
        int ad = ((C ^ ((C >> 4) & 15)) << 4) + ((ep & 4) << 1);
        *(unsigned long long*)(LDS + ad)          = pe;
        *(unsigned long long*)(LDS + EBYTES + ad) = po;
      }
    }
  }
  __syncthreads();

  // ---- A frag-major bases (L2-resident) ----
  const char* AgE = (const char*)bi2f + (long)(g * 256 + wm * 4) * 1024 + l * 16;
  const char* AgO = AgE + 131072;

  int C0[4];
  #pragma unroll
  for (int j = 0; j < 4; ++j) C0[j] = (wn * 64 + j * 16 + x) * 16 + h;

  f32x4 accE[4][4] = {}, accO[4][4] = {};
  bf16x8 aE[2][4], aO[2][4];
  #pragma unroll
  for (int i = 0; i < 4; ++i){
    aE[0][i] = *(const bf16x8*)(AgE + i * 1024);
    aO[0][i] = *(const bf16x8*)(AgO + i * 1024);
  }

  #pragma unroll
  for (int s = 0; s < 16; ++s){
    const int cur = s & 1, nxt = cur ^ 1;
    if (s < 15){
      #pragma unroll
      for (int i = 0; i < 4; ++i){
        aE[nxt][i] = *(const bf16x8*)(AgE + (s + 1) * 8192 + i * 1024);
        aO[nxt][i] = *(const bf16x8*)(AgO + (s + 1) * 8192 + i * 1024);
      }
    }
    bf16x8 bqE[4], bqO[4];
    #pragma unroll
    for (int j = 0; j < 4; ++j){
      int C  = C0[j] + s * 4;
      int ad = (C ^ ((C >> 4) & 15)) << 4;
      bqE[j] = *(const bf16x8*)(LDS + ad);
      bqO[j] = *(const bf16x8*)(LDS + EBYTES + ad);
    }
    __builtin_amdgcn_s_setprio(1);
    #pragma unroll
    for (int i = 0; i < 4; ++i)
      #pragma unroll
      for (int j = 0; j < 4; ++j)
        accE[i][j] = __builtin_amdgcn_mfma_f32_16x16x32_bf16(aE[cur][i], bqE[j], accE[i][j], 0, 0, 0);
    #pragma unroll
    for (int i = 0; i < 4; ++i)
      #pragma unroll
      for (int j = 0; j < 4; ++j)
        accO[i][j] = __builtin_amdgcn_mfma_f32_16x16x32_bf16(aO[cur][i], bqO[j], accO[i][j], 0, 0, 0);
    __builtin_amdgcn_s_setprio(0);
  }

  // ---- transpose fill: u32 tile [128 tl][64 slots], f = slot ^ ((tl&7)<<2) ----
  // direct slot cp1 = wm*16+i*4+h holds (X[c0],X[c0+1]), c0 = 64g+2*cp1
  // mirror slot 63-cp1 holds (X[511-c0],X[512-c0]) -> phys p = 518-64g-2*cp1, +1
  // bank(f) spans h (bits 0-1) x (tl&7 XOR, bits 2-4): 2 lanes/bank = conflict-free
  __syncthreads();   // all K-loop LDS reads done; safe to overwrite audio planes
  #pragma unroll
  for (int i = 0; i < 4; ++i){
    int cp1 = wm * 16 + i * 4 + h;          // 0..31
    int mp  = 63 - cp1;                     // 32..63
    #pragma unroll
    for (int j = 0; j < 4; ++j){
      int tl = wn * 64 + j * 16 + x;
      f32x4 E = accE[i][j], O = accO[i][j];
      float m1 = sqrtf((E[0]+O[0])*(E[0]+O[0]) + (E[1]+O[1])*(E[1]+O[1]));  // X[c0]
      float m2 = sqrtf((E[2]+O[2])*(E[2]+O[2]) + (E[3]+O[3])*(E[3]+O[3]));  // X[c0+1]
      float m3 = sqrtf((E[0]-O[0])*(E[0]-O[0]) + (E[1]-O[1])*(E[1]-O[1]));  // X[512-c0]
      float m4 = sqrtf((E[2]-O[2])*(E[2]-O[2]) + (E[3]-O[3])*(E[3]-O[3]));  // X[511-c0]
      unsigned p1 = (unsigned)f2bf(m1) | ((unsigned)f2bf(m2) << 16);
      unsigned p2 = (unsigned)f2bf(m4) | ((unsigned)f2bf(m3) << 16);
      int xs = (tl & 7) << 2;
      *(unsigned*)(LDS + tl * 256 + ((cp1 ^ xs) << 2)) = p1;
      *(unsigned*)(LDS + tl * 256 + ((mp  ^ xs) << 2)) = p2;
    }
  }
  __syncthreads();

  // ---- coalesced readout: 8 passes, 16B/thread; direct p=64g+.., mirror p from 456-64g ----
  {
    const long rowbase = (long)(nt * 128) * CPAD;
    int slot8 = tid & 15, rr = tid >> 4;
    int cb0 = (slot8 < 8) ? (64 * g + slot8 * 8) : (392 - 64 * g + slot8 * 8);
    #pragma unroll
    for (int pass = 0; pass < 8; ++pass){
      int tl = pass * 16 + rr;
      int f4 = (slot8 * 4) ^ ((tl & 7) << 2);
      i32x4 vv = *(const i32x4*)(LDS + tl * 256 + f4 * 4);
      *(i32x4*)((char*)magT + (rowbase + (long)tl * CPAD + cb0) * 2) = vv;
    }
  }
}

// ---------- k_mel: [80][576] x [576][t] + log(clip) -> out [32][80][1024] f32 ----------
__launch_bounds__(256)
__global__ void k_mel(const unsigned short* __restrict__ wb,
                      const unsigned short* __restrict__ magT,
                      float* __restrict__ out){
  __shared__ unsigned short Ws[80 * 32];
  __shared__ unsigned short Ms[128 * 32];
  int tid  = threadIdx.x, lane = tid & 63, wid = tid >> 6;
  int bx   = blockIdx.x;
  int bt   = bx & 7, b = bx >> 3;
  int t0   = bt * 128;
  f32x4 acc[5][2] = {};
  const char* Mb = (const char*)(magT + ((long)b * 1024 + t0) * CPAD);
  const char* Wb = (const char*)wb;

  for (int kt = 0; kt < 18; ++kt){
    int k0b = kt * 64;
    {
      int o = tid * 16;
      gload_lds16(Wb + (o >> 6) * 1152 + k0b + (o & 63), (char*)Ws + wid * 1024);
      if (wid == 0){
        int o2 = 4096 + lane * 16;
        gload_lds16(Wb + (o2 >> 6) * 1152 + k0b + (o2 & 63), (char*)Ws + 4096);
      }
    }
    #pragma unroll
    for (int q = 0; q < 2; ++q){
      int o = (q * 256 + tid) * 16;
      gload_lds16(Mb + (long)(o >> 6) * 1152 + k0b + (o & 63), (char*)Ms + q * 4096 + wid * 1024);
    }
    __syncthreads();
    bf16x8 af[5], bfr[2];
    int kb = (lane >> 4) << 4;
    #pragma unroll
    for (int i = 0; i < 5; ++i)
      af[i] = *(const bf16x8*)((const char*)Ws + (i*16 + (lane & 15)) * 64 + kb);
    #pragma unroll
    for (int j = 0; j < 2; ++j)
      bfr[j] = *(const bf16x8*)((const char*)Ms + (wid*32 + j*16 + (lane & 15)) * 64 + kb);
    #pragma unroll
    for (int i = 0; i < 5; ++i)
      #pragma unroll
      for (int j = 0; j < 2; ++j)
        acc[i][j] = __builtin_amdgcn_mfma_f32_16x16x32_bf16(af[i], bfr[j], acc[i][j], 0, 0, 0);
    __syncthreads();
  }
  #pragma unroll
  for (int i = 0; i < 5; ++i)
    #pragma unroll
    for (int j = 0; j < 2; ++j){
      int m = i*16 + ((lane >> 4) << 2);
      int t = t0 + wid*32 + j*16 + (lane & 15);
      #pragma unroll
      for (int r = 0; r < 4; ++r){
        float v = acc[i][j][r];
        out[((long)b * NMELS + (m + r)) * 1024 + t] = logf(fmaxf(v, 1e-5f));
      }
    }
}

__global__ void k_sentinel(float* out, int n){
  int i = blockIdx.x * 256 + threadIdx.x;
  if (i < n) out[i] = 12345.0f;
}

extern "C" void kernel_launch(void* const* d_in, const int* in_sizes, int n_in,
                              void* d_out, int out_size, void* d_ws, size_t ws_size,
                              hipStream_t stream){
  const float* audio = (const float*)d_in[0];
  const float* basis = (const float*)d_in[1];
  const float* melw  = (const float*)d_in[2];
  float* out = (float*)d_out;

  size_t off_bi  = 0;                                            // bi2f: 1 MB
  size_t off_wb  = (size_t)1024 * 1024;
  size_t off_mag = off_wb + (size_t)NMELS * CPAD * 2;
  size_t total   = off_mag + (size_t)32 * 1024 * CPAD * 2;       // ~38.9 MB

  if (ws_size < total){
    k_sentinel<<<(out_size + 255) / 256, 256, 0, stream>>>(out, out_size);
    return;
  }
  char* ws = (char*)d_ws;
  unsigned short* bi2f = (unsigned short*)(ws + off_bi);
  unsigned short* wb   = (unsigned short*)(ws + off_wb);
  unsigned short* magT = (unsigned short*)(ws + off_mag);

  k_extra <<<16384, 256, 0, stream>>>(audio, basis, magT);
  k_basis4<<<  256, 256, 0, stream>>>(basis, bi2f);
  k_w     <<<  180, 256, 0, stream>>>(melw, wb);
  k_stft  <<< 1024, 256, 0, stream>>>(bi2f, audio, magT);
  k_mel   <<<  256, 256, 0, stream>>>(wb, magT, out);
}